// Round 4
// baseline (2482.616 us; speedup 1.0000x reference)
//
#include <hip/hip_runtime.h>
#include <hip/hip_bf16.h>
#include <math.h>

typedef __hip_bfloat16 bf16;

#define N_NODES 10000
#define N_EDGES 160000
#define IN_C    768
#define H1DIM   1024      // HEADS * HID
#define HEADS   4
#define OUT_C   256
#define NEG_SLOPE 0.2f

__device__ __forceinline__ float b2f(bf16 v) { return __bfloat162float(v); }
__device__ __forceinline__ float u2f(unsigned short u) { return __uint_as_float(((unsigned)u) << 16); }
__device__ __forceinline__ float ld(const bf16* p) { return __bfloat162float(*p); }
__device__ __forceinline__ float ld(const float* p) { return *p; }

// ---------------- edge-index dtype probe + normalize ----------------
// If the edge buffer is int64 (little-endian, all values < 2^31), every odd
// int32 word among the first 2*N_EDGES words is 0. If int32, those words are
// random node ids (certainly not all zero across 160000 words).
__global__ void detect_i64(const int* __restrict__ raw, int* __restrict__ flag) {
    const int i = blockIdx.x * blockDim.x + threadIdx.x;   // i in [0, N_EDGES)
    if (i >= N_EDGES) return;
    if (raw[2 * i + 1] != 0) atomicAnd(flag, 0);
}

__global__ void normalize_ei(const int* __restrict__ raw, const int* __restrict__ flag,
                             int* __restrict__ ei) {
    const int i = blockIdx.x * blockDim.x + threadIdx.x;   // i in [0, 2*N_EDGES)
    if (i >= 2 * N_EDGES) return;
    ei[i] = (*flag) ? raw[2 * i] : raw[i];
}

// ---------------- CSR build ----------------
__global__ void count_deg(const int* __restrict__ ei, int* __restrict__ deg_d, int* __restrict__ deg_s) {
    const int e = blockIdx.x * blockDim.x + threadIdx.x;
    if (e >= N_EDGES) return;
    atomicAdd(&deg_d[ei[N_EDGES + e]], 1);   // layer-1 segment: edge_index[1]
    atomicAdd(&deg_s[ei[e]], 1);             // layer-2 segment: edge_index[0]
}

__global__ __launch_bounds__(1024) void scan_excl(const int* __restrict__ deg, int* __restrict__ offs, int n) {
    __shared__ int sh[1024];
    __shared__ int carry_sh;
    const int t = threadIdx.x;
    if (t == 0) carry_sh = 0;
    __syncthreads();
    for (int base = 0; base < n; base += 1024) {
        const int i = base + t;
        const int v = (i < n) ? deg[i] : 0;
        sh[t] = v;
        __syncthreads();
        for (int o = 1; o < 1024; o <<= 1) {
            const int x = (t >= o) ? sh[t - o] : 0;
            __syncthreads();
            sh[t] += x;
            __syncthreads();
        }
        const int carry = carry_sh;
        if (i < n) offs[i] = carry + sh[t] - v;   // exclusive
        __syncthreads();
        if (t == 0) carry_sh = carry + sh[1023];
        __syncthreads();
    }
    if (t == 0) offs[n] = carry_sh;
}

__global__ void fill_csr(const int* __restrict__ ei,
                         const int* __restrict__ offs_d, const int* __restrict__ offs_s,
                         int* __restrict__ cur_d, int* __restrict__ cur_s,
                         int* __restrict__ eid_d, int* __restrict__ eid_s) {
    const int e = blockIdx.x * blockDim.x + threadIdx.x;
    if (e >= N_EDGES) return;
    const int d = ei[N_EDGES + e];
    const int p = atomicAdd(&cur_d[d], 1);
    eid_d[offs_d[d] + p] = e;
    const int s = ei[e];
    const int q = atomicAdd(&cur_s[s], 1);
    eid_s[offs_s[s] + q] = e;
}

// ---------------- GEMM: C[M,N] = A[M,K] @ B[K,N], fp32 acc, bf16 out ----------------
template <typename TA, typename TB>
__global__ __launch_bounds__(256) void gemm_any(const TA* __restrict__ A,
                                                const TB* __restrict__ B,
                                                bf16* __restrict__ C,
                                                int M, int N, int K) {
    __shared__ float As[16][68];
    __shared__ float Bs[16][68];
    const int tid = threadIdx.x;
    const int bm = blockIdx.y * 64;
    const int bn = blockIdx.x * 64;
    const int ty = tid >> 4;
    const int tx = tid & 15;
    float acc[4][4] = {};

    for (int k0 = 0; k0 < K; k0 += 16) {
        {
            const int r  = tid >> 2;
            const int kk = (tid & 3) << 2;
            const int gr = bm + r;
            float v0 = 0.f, v1 = 0.f, v2 = 0.f, v3 = 0.f;
            if (gr < M) {
                const TA* p = A + (size_t)gr * K + k0 + kk;
                v0 = ld(p); v1 = ld(p + 1); v2 = ld(p + 2); v3 = ld(p + 3);
            }
            As[kk + 0][r] = v0; As[kk + 1][r] = v1;
            As[kk + 2][r] = v2; As[kk + 3][r] = v3;
        }
        {
            const int r = tid >> 4;
            const int c = (tid & 15) << 2;
            const TB* p = B + (size_t)(k0 + r) * N + bn + c;
            Bs[r][c + 0] = ld(p); Bs[r][c + 1] = ld(p + 1);
            Bs[r][c + 2] = ld(p + 2); Bs[r][c + 3] = ld(p + 3);
        }
        __syncthreads();
        #pragma unroll
        for (int kk = 0; kk < 16; ++kk) {
            const float a0 = As[kk][ty * 4 + 0], a1 = As[kk][ty * 4 + 1];
            const float a2 = As[kk][ty * 4 + 2], a3 = As[kk][ty * 4 + 3];
            const float b0 = Bs[kk][tx * 4 + 0], b1 = Bs[kk][tx * 4 + 1];
            const float b2 = Bs[kk][tx * 4 + 2], b3 = Bs[kk][tx * 4 + 3];
            acc[0][0] += a0 * b0; acc[0][1] += a0 * b1; acc[0][2] += a0 * b2; acc[0][3] += a0 * b3;
            acc[1][0] += a1 * b0; acc[1][1] += a1 * b1; acc[1][2] += a1 * b2; acc[1][3] += a1 * b3;
            acc[2][0] += a2 * b0; acc[2][1] += a2 * b1; acc[2][2] += a2 * b2; acc[2][3] += a2 * b3;
            acc[3][0] += a3 * b0; acc[3][1] += a3 * b1; acc[3][2] += a3 * b2; acc[3][3] += a3 * b3;
        }
        __syncthreads();
    }
    #pragma unroll
    for (int i = 0; i < 4; ++i) {
        const int gr = bm + ty * 4 + i;
        if (gr < M) {
            bf16* cp = C + (size_t)gr * N + bn + tx * 4;
            cp[0] = __float2bfloat16(acc[i][0]);
            cp[1] = __float2bfloat16(acc[i][1]);
            cp[2] = __float2bfloat16(acc[i][2]);
            cp[3] = __float2bfloat16(acc[i][3]);
        }
    }
}

// ---------------- attention dots: one wave per row of 256 ----------------
__global__ __launch_bounds__(256) void att_dots(const bf16* __restrict__ h,
                                                const float* __restrict__ ws_,
                                                const float* __restrict__ wd_,
                                                float* __restrict__ a_s,
                                                float* __restrict__ a_d,
                                                int rows, int heads) {
    const int r = blockIdx.x * 4 + (threadIdx.x >> 6);
    if (r >= rows) return;
    const int lane = threadIdx.x & 63;
    const int hd = r % heads;
    const bf16* hp = h + (size_t)r * 256 + lane * 4;
    const float* sp = ws_ + hd * 256 + lane * 4;
    const float* dp = wd_ + hd * 256 + lane * 4;
    float ss = 0.f, sd = 0.f;
    #pragma unroll
    for (int i = 0; i < 4; ++i) {
        const float v = b2f(hp[i]);
        ss += v * sp[i];
        sd += v * dp[i];
    }
    #pragma unroll
    for (int o = 32; o > 0; o >>= 1) {
        ss += __shfl_xor(ss, o);
        sd += __shfl_xor(sd, o);
    }
    if (lane == 0) { a_s[r] = ss; a_d[r] = sd; }
}

// ---------------- layer 1: per-node softmax + gather + bias + ELU ----------------
__global__ __launch_bounds__(256) void gat_gather1(
    const int* __restrict__ ei, const int* __restrict__ offs, const int* __restrict__ eid,
    const bf16* __restrict__ h1, const float* __restrict__ a_s, const float* __restrict__ a_d,
    const float* __restrict__ bias, bf16* __restrict__ outp)
{
    const int n = blockIdx.x;
    const int beg = offs[n];
    const int deg = offs[n + 1] - beg;
    const int t = threadIdx.x, lane = t & 63, wave = t >> 6;
    __shared__ float m_sh[HEADS], den_sh[HEADS];
    __shared__ float al_sh[64][HEADS];
    __shared__ int   src_sh[64];

    if (wave == 0 && deg > 0) {
        float adv[HEADS];
        #pragma unroll
        for (int h = 0; h < HEADS; ++h) adv[h] = a_d[n * HEADS + h];
        float mx[HEADS];
        #pragma unroll
        for (int h = 0; h < HEADS; ++h) mx[h] = -INFINITY;
        for (int k = lane; k < deg; k += 64) {
            const int e = eid[beg + k];
            const int s = ei[e];
            #pragma unroll
            for (int h = 0; h < HEADS; ++h) {
                float v = a_s[s * HEADS + h] + adv[h];
                v = v > 0.f ? v : NEG_SLOPE * v;
                mx[h] = fmaxf(mx[h], v);
            }
        }
        #pragma unroll
        for (int o = 32; o > 0; o >>= 1)
            #pragma unroll
            for (int h = 0; h < HEADS; ++h) mx[h] = fmaxf(mx[h], __shfl_xor(mx[h], o));
        float sm[HEADS] = {0.f, 0.f, 0.f, 0.f};
        for (int k = lane; k < deg; k += 64) {
            const int e = eid[beg + k];
            const int s = ei[e];
            #pragma unroll
            for (int h = 0; h < HEADS; ++h) {
                float v = a_s[s * HEADS + h] + adv[h];
                v = v > 0.f ? v : NEG_SLOPE * v;
                sm[h] += __expf(v - mx[h]);
            }
        }
        #pragma unroll
        for (int o = 32; o > 0; o >>= 1)
            #pragma unroll
            for (int h = 0; h < HEADS; ++h) sm[h] += __shfl_xor(sm[h], o);
        if (lane == 0) {
            #pragma unroll
            for (int h = 0; h < HEADS; ++h) { m_sh[h] = mx[h]; den_sh[h] = sm[h] + 1e-16f; }
        }
    }
    __syncthreads();

    float acc0 = 0.f, acc1 = 0.f, acc2 = 0.f, acc3 = 0.f;
    const int myh = t >> 6;   // thread t owns channels 4t..4t+3, all in head t/64
    for (int bs = 0; bs < deg; bs += 64) {
        const int cnt = min(64, deg - bs);
        if (wave == 0 && lane < cnt) {
            const int e = eid[beg + bs + lane];
            const int s = ei[e];
            src_sh[lane] = s;
            #pragma unroll
            for (int h = 0; h < HEADS; ++h) {
                float v = a_s[s * HEADS + h] + a_d[n * HEADS + h];
                v = v > 0.f ? v : NEG_SLOPE * v;
                al_sh[lane][h] = __expf(v - m_sh[h]) / den_sh[h];
            }
        }
        __syncthreads();
        for (int k = 0; k < cnt; ++k) {
            const int s = src_sh[k];
            const float al = al_sh[k][myh];
            const ushort4 hv = *((const ushort4*)(h1 + (size_t)s * H1DIM) + t);
            acc0 += u2f(hv.x) * al; acc1 += u2f(hv.y) * al;
            acc2 += u2f(hv.z) * al; acc3 += u2f(hv.w) * al;
        }
        __syncthreads();
    }
    float v0 = acc0 + bias[t * 4 + 0];
    float v1 = acc1 + bias[t * 4 + 1];
    float v2 = acc2 + bias[t * 4 + 2];
    float v3 = acc3 + bias[t * 4 + 3];
    v0 = v0 > 0.f ? v0 : expm1f(v0);
    v1 = v1 > 0.f ? v1 : expm1f(v1);
    v2 = v2 > 0.f ? v2 : expm1f(v2);
    v3 = v3 > 0.f ? v3 : expm1f(v3);
    bf16* op = outp + (size_t)n * H1DIM + t * 4;
    op[0] = __float2bfloat16(v0); op[1] = __float2bfloat16(v1);
    op[2] = __float2bfloat16(v2); op[3] = __float2bfloat16(v3);
}

// ---------------- layer 2: per-node softmax + gather + bias, fp32 out ----------------
__global__ __launch_bounds__(256) void gat_gather2(
    const int* __restrict__ ei, const int* __restrict__ offs, const int* __restrict__ eid,
    const bf16* __restrict__ h2, const float* __restrict__ a_s, const float* __restrict__ a_d,
    const float* __restrict__ bias, float* __restrict__ outp)
{
    const int n = blockIdx.x;
    const int beg = offs[n];
    const int deg = offs[n + 1] - beg;
    const int t = threadIdx.x, lane = t & 63, wave = t >> 6;
    __shared__ float m_sh, den_sh;
    __shared__ float al_sh[64];
    __shared__ int   src_sh[64];

    if (wave == 0 && deg > 0) {
        const float adn = a_d[n];
        float mx = -INFINITY;
        for (int k = lane; k < deg; k += 64) {
            const int e = eid[beg + k];
            const int s = ei[N_EDGES + e];     // layer-2 message source = edge_index[1]
            float v = a_s[s] + adn;
            v = v > 0.f ? v : NEG_SLOPE * v;
            mx = fmaxf(mx, v);
        }
        #pragma unroll
        for (int o = 32; o > 0; o >>= 1) mx = fmaxf(mx, __shfl_xor(mx, o));
        float sm = 0.f;
        for (int k = lane; k < deg; k += 64) {
            const int e = eid[beg + k];
            const int s = ei[N_EDGES + e];
            float v = a_s[s] + adn;
            v = v > 0.f ? v : NEG_SLOPE * v;
            sm += __expf(v - mx);
        }
        #pragma unroll
        for (int o = 32; o > 0; o >>= 1) sm += __shfl_xor(sm, o);
        if (lane == 0) { m_sh = mx; den_sh = sm + 1e-16f; }
    }
    __syncthreads();

    float acc = 0.f;
    for (int bs = 0; bs < deg; bs += 64) {
        const int cnt = min(64, deg - bs);
        if (wave == 0 && lane < cnt) {
            const int e = eid[beg + bs + lane];
            const int s = ei[N_EDGES + e];
            src_sh[lane] = s;
            float v = a_s[s] + a_d[n];
            v = v > 0.f ? v : NEG_SLOPE * v;
            al_sh[lane] = __expf(v - m_sh) / den_sh;
        }
        __syncthreads();
        for (int k = 0; k < cnt; ++k) {
            acc += b2f(h2[(size_t)src_sh[k] * OUT_C + t]) * al_sh[k];
        }
        __syncthreads();
    }
    outp[(size_t)n * OUT_C + t] = acc + bias[t];
}

extern "C" void kernel_launch(void* const* d_in, const int* in_sizes, int n_in,
                              void* d_out, int out_size, void* d_ws, size_t ws_size,
                              hipStream_t stream) {
    (void)in_sizes; (void)n_in; (void)out_size; (void)ws_size;
    const float* x        = (const float*)d_in[0];
    const int*   ei_raw   = (const int*)d_in[1];
    const float* W1       = (const float*)d_in[2];
    const float* att_src1 = (const float*)d_in[3];
    const float* att_dst1 = (const float*)d_in[4];
    const float* b1       = (const float*)d_in[5];
    const float* W2       = (const float*)d_in[6];
    const float* att_src2 = (const float*)d_in[7];
    const float* att_dst2 = (const float*)d_in[8];
    const float* b2       = (const float*)d_in[9];
    float* out = (float*)d_out;

    // ---- workspace carve (all 256B-aligned); total ~51 MB ----
    char* base = (char*)d_ws;
    size_t woff = 0;
    auto carve = [&](size_t bytes) -> char* {
        char* p = base + woff;
        woff += (bytes + 255) & ~(size_t)255;
        return p;
    };
    bf16* h1   = (bf16*)carve((size_t)N_NODES * H1DIM * 2);   // 20.48 MB
    bf16* a2   = (bf16*)carve((size_t)N_NODES * H1DIM * 2);   // 20.48 MB
    bf16* h2   = (bf16*)carve((size_t)N_NODES * OUT_C * 2);   //  5.12 MB
    float* as1 = (float*)carve((size_t)N_NODES * HEADS * 4);
    float* ad1 = (float*)carve((size_t)N_NODES * HEADS * 4);
    float* as2 = (float*)carve((size_t)N_NODES * 4);
    float* ad2 = (float*)carve((size_t)N_NODES * 4);
    int* degs  = (int*)carve((size_t)4 * N_NODES * 4);        // deg_d, deg_s, cur_d, cur_s
    int* deg_d = degs;
    int* deg_s = degs + N_NODES;
    int* cur_d = degs + 2 * N_NODES;
    int* cur_s = degs + 3 * N_NODES;
    int* offs_d = (int*)carve((size_t)(N_NODES + 1) * 4);
    int* offs_s = (int*)carve((size_t)(N_NODES + 1) * 4);
    int* eid_d  = (int*)carve((size_t)N_EDGES * 4);
    int* eid_s  = (int*)carve((size_t)N_EDGES * 4);
    int* ei     = (int*)carve((size_t)2 * N_EDGES * 4);       // normalized int32 edge index
    int* flag   = (int*)carve(256);

    // ---- edge dtype probe + normalize ----
    {
        const int one = 1;  // flag := 1 (assume int64) then AND with evidence
        hipMemcpyAsync(flag, &one, sizeof(int), hipMemcpyHostToDevice, stream);
    }
    detect_i64<<<(N_EDGES + 255) / 256, 256, 0, stream>>>(ei_raw, flag);
    normalize_ei<<<(2 * N_EDGES + 255) / 256, 256, 0, stream>>>(ei_raw, flag, ei);

    // ---- CSR build ----
    hipMemsetAsync(degs, 0, (size_t)4 * N_NODES * 4, stream);
    count_deg<<<(N_EDGES + 255) / 256, 256, 0, stream>>>(ei, deg_d, deg_s);
    scan_excl<<<1, 1024, 0, stream>>>(deg_d, offs_d, N_NODES);
    scan_excl<<<1, 1024, 0, stream>>>(deg_s, offs_s, N_NODES);
    fill_csr<<<(N_EDGES + 255) / 256, 256, 0, stream>>>(ei, offs_d, offs_s, cur_d, cur_s, eid_d, eid_s);

    // ---- layer 1 ----
    gemm_any<float, float><<<dim3(H1DIM / 64, (N_NODES + 63) / 64), 256, 0, stream>>>(
        x, W1, h1, N_NODES, H1DIM, IN_C);
    att_dots<<<(N_NODES * HEADS + 3) / 4, 256, 0, stream>>>(
        h1, att_src1, att_dst1, as1, ad1, N_NODES * HEADS, HEADS);
    gat_gather1<<<N_NODES, 256, 0, stream>>>(ei, offs_d, eid_d, h1, as1, ad1, b1, a2);

    // ---- layer 2 ----
    gemm_any<bf16, float><<<dim3(OUT_C / 64, (N_NODES + 63) / 64), 256, 0, stream>>>(
        a2, W2, h2, N_NODES, OUT_C, H1DIM);
    att_dots<<<(N_NODES + 3) / 4, 256, 0, stream>>>(
        h2, att_src2, att_dst2, as2, ad2, N_NODES, 1);
    gat_gather2<<<N_NODES, 256, 0, stream>>>(ei, offs_s, eid_s, h2, as2, ad2, b2, out);
}

// Round 5
// 613.472 us; speedup vs baseline: 4.0468x; 4.0468x over previous
//
#include <hip/hip_runtime.h>
#include <hip/hip_bf16.h>
#include <math.h>

typedef __hip_bfloat16 bf16;

#define N_NODES 10000
#define N_EDGES 160000
#define IN_C    768
#define H1DIM   1024      // HEADS * HID
#define HEADS   4
#define OUT_C   256
#define NEG_SLOPE 0.2f

__device__ __forceinline__ float b2f(bf16 v) { return __bfloat162float(v); }
__device__ __forceinline__ float u2f(unsigned short u) { return __uint_as_float(((unsigned)u) << 16); }
__device__ __forceinline__ float ld(const bf16* p) { return __bfloat162float(*p); }
__device__ __forceinline__ float ld(const float* p) { return *p; }

// ---------------- CSR build ----------------
__global__ void count_deg(const int* __restrict__ ei, int* __restrict__ deg_d, int* __restrict__ deg_s) {
    const int e = blockIdx.x * blockDim.x + threadIdx.x;
    if (e >= N_EDGES) return;
    atomicAdd(&deg_d[ei[N_EDGES + e]], 1);   // layer-1 segment: edge_index[1]
    atomicAdd(&deg_s[ei[e]], 1);             // layer-2 segment: edge_index[0]
}

__global__ __launch_bounds__(1024) void scan_excl(const int* __restrict__ deg, int* __restrict__ offs, int n) {
    __shared__ int sh[1024];
    __shared__ int carry_sh;
    const int t = threadIdx.x;
    if (t == 0) carry_sh = 0;
    __syncthreads();
    for (int base = 0; base < n; base += 1024) {
        const int i = base + t;
        const int v = (i < n) ? deg[i] : 0;
        sh[t] = v;
        __syncthreads();
        for (int o = 1; o < 1024; o <<= 1) {
            const int x = (t >= o) ? sh[t - o] : 0;
            __syncthreads();
            sh[t] += x;
            __syncthreads();
        }
        const int carry = carry_sh;
        if (i < n) offs[i] = carry + sh[t] - v;   // exclusive
        __syncthreads();
        if (t == 0) carry_sh = carry + sh[1023];
        __syncthreads();
    }
    if (t == 0) offs[n] = carry_sh;
}

__global__ void fill_csr(const int* __restrict__ ei,
                         const int* __restrict__ offs_d, const int* __restrict__ offs_s,
                         int* __restrict__ cur_d, int* __restrict__ cur_s,
                         int* __restrict__ eid_d, int* __restrict__ eid_s) {
    const int e = blockIdx.x * blockDim.x + threadIdx.x;
    if (e >= N_EDGES) return;
    const int d = ei[N_EDGES + e];
    const int p = atomicAdd(&cur_d[d], 1);
    eid_d[offs_d[d] + p] = e;
    const int s = ei[e];
    const int q = atomicAdd(&cur_s[s], 1);
    eid_s[offs_s[s] + q] = e;
}

// ---------------- GEMM: C[M,N] = A[M,K] @ B[K,N], fp32 acc, bf16 out ----------------
template <typename TA, typename TB>
__global__ __launch_bounds__(256) void gemm_any(const TA* __restrict__ A,
                                                const TB* __restrict__ B,
                                                bf16* __restrict__ C,
                                                int M, int N, int K) {
    __shared__ float As[16][68];
    __shared__ float Bs[16][68];
    const int tid = threadIdx.x;
    const int bm = blockIdx.y * 64;
    const int bn = blockIdx.x * 64;
    const int ty = tid >> 4;
    const int tx = tid & 15;
    float acc[4][4] = {};

    for (int k0 = 0; k0 < K; k0 += 16) {
        {
            const int r  = tid >> 2;
            const int kk = (tid & 3) << 2;
            const int gr = bm + r;
            float v0 = 0.f, v1 = 0.f, v2 = 0.f, v3 = 0.f;
            if (gr < M) {
                const TA* p = A + (size_t)gr * K + k0 + kk;
                v0 = ld(p); v1 = ld(p + 1); v2 = ld(p + 2); v3 = ld(p + 3);
            }
            As[kk + 0][r] = v0; As[kk + 1][r] = v1;
            As[kk + 2][r] = v2; As[kk + 3][r] = v3;
        }
        {
            const int r = tid >> 4;
            const int c = (tid & 15) << 2;
            const TB* p = B + (size_t)(k0 + r) * N + bn + c;
            Bs[r][c + 0] = ld(p); Bs[r][c + 1] = ld(p + 1);
            Bs[r][c + 2] = ld(p + 2); Bs[r][c + 3] = ld(p + 3);
        }
        __syncthreads();
        #pragma unroll
        for (int kk = 0; kk < 16; ++kk) {
            const float a0 = As[kk][ty * 4 + 0], a1 = As[kk][ty * 4 + 1];
            const float a2 = As[kk][ty * 4 + 2], a3 = As[kk][ty * 4 + 3];
            const float b0 = Bs[kk][tx * 4 + 0], b1 = Bs[kk][tx * 4 + 1];
            const float b2 = Bs[kk][tx * 4 + 2], b3 = Bs[kk][tx * 4 + 3];
            acc[0][0] += a0 * b0; acc[0][1] += a0 * b1; acc[0][2] += a0 * b2; acc[0][3] += a0 * b3;
            acc[1][0] += a1 * b0; acc[1][1] += a1 * b1; acc[1][2] += a1 * b2; acc[1][3] += a1 * b3;
            acc[2][0] += a2 * b0; acc[2][1] += a2 * b1; acc[2][2] += a2 * b2; acc[2][3] += a2 * b3;
            acc[3][0] += a3 * b0; acc[3][1] += a3 * b1; acc[3][2] += a3 * b2; acc[3][3] += a3 * b3;
        }
        __syncthreads();
    }
    #pragma unroll
    for (int i = 0; i < 4; ++i) {
        const int gr = bm + ty * 4 + i;
        if (gr < M) {
            bf16* cp = C + (size_t)gr * N + bn + tx * 4;
            cp[0] = __float2bfloat16(acc[i][0]);
            cp[1] = __float2bfloat16(acc[i][1]);
            cp[2] = __float2bfloat16(acc[i][2]);
            cp[3] = __float2bfloat16(acc[i][3]);
        }
    }
}

// ---------------- attention dots: one wave per row of 256 ----------------
__global__ __launch_bounds__(256) void att_dots(const bf16* __restrict__ h,
                                                const float* __restrict__ ws_,
                                                const float* __restrict__ wd_,
                                                float* __restrict__ a_s,
                                                float* __restrict__ a_d,
                                                int rows, int heads) {
    const int r = blockIdx.x * 4 + (threadIdx.x >> 6);
    if (r >= rows) return;
    const int lane = threadIdx.x & 63;
    const int hd = r % heads;
    const bf16* hp = h + (size_t)r * 256 + lane * 4;
    const float* sp = ws_ + hd * 256 + lane * 4;
    const float* dp = wd_ + hd * 256 + lane * 4;
    float ss = 0.f, sd = 0.f;
    #pragma unroll
    for (int i = 0; i < 4; ++i) {
        const float v = b2f(hp[i]);
        ss += v * sp[i];
        sd += v * dp[i];
    }
    #pragma unroll
    for (int o = 32; o > 0; o >>= 1) {
        ss += __shfl_xor(ss, o);
        sd += __shfl_xor(sd, o);
    }
    if (lane == 0) { a_s[r] = ss; a_d[r] = sd; }
}

// ---------------- layer 1: per-node softmax + gather + bias + ELU ----------------
__global__ __launch_bounds__(256) void gat_gather1(
    const int* __restrict__ ei, const int* __restrict__ offs, const int* __restrict__ eid,
    const bf16* __restrict__ h1, const float* __restrict__ a_s, const float* __restrict__ a_d,
    const float* __restrict__ bias, bf16* __restrict__ outp)
{
    const int n = blockIdx.x;
    const int beg = offs[n];
    const int deg = offs[n + 1] - beg;
    const int t = threadIdx.x, lane = t & 63, wave = t >> 6;
    __shared__ float m_sh[HEADS], den_sh[HEADS];
    __shared__ float al_sh[64][HEADS];
    __shared__ int   src_sh[64];

    if (wave == 0 && deg > 0) {
        float adv[HEADS];
        #pragma unroll
        for (int h = 0; h < HEADS; ++h) adv[h] = a_d[n * HEADS + h];
        float mx[HEADS];
        #pragma unroll
        for (int h = 0; h < HEADS; ++h) mx[h] = -INFINITY;
        for (int k = lane; k < deg; k += 64) {
            const int e = eid[beg + k];
            const int s = ei[e];
            #pragma unroll
            for (int h = 0; h < HEADS; ++h) {
                float v = a_s[s * HEADS + h] + adv[h];
                v = v > 0.f ? v : NEG_SLOPE * v;
                mx[h] = fmaxf(mx[h], v);
            }
        }
        #pragma unroll
        for (int o = 32; o > 0; o >>= 1)
            #pragma unroll
            for (int h = 0; h < HEADS; ++h) mx[h] = fmaxf(mx[h], __shfl_xor(mx[h], o));
        float sm[HEADS] = {0.f, 0.f, 0.f, 0.f};
        for (int k = lane; k < deg; k += 64) {
            const int e = eid[beg + k];
            const int s = ei[e];
            #pragma unroll
            for (int h = 0; h < HEADS; ++h) {
                float v = a_s[s * HEADS + h] + adv[h];
                v = v > 0.f ? v : NEG_SLOPE * v;
                sm[h] += __expf(v - mx[h]);
            }
        }
        #pragma unroll
        for (int o = 32; o > 0; o >>= 1)
            #pragma unroll
            for (int h = 0; h < HEADS; ++h) sm[h] += __shfl_xor(sm[h], o);
        if (lane == 0) {
            #pragma unroll
            for (int h = 0; h < HEADS; ++h) { m_sh[h] = mx[h]; den_sh[h] = sm[h] + 1e-16f; }
        }
    }
    __syncthreads();

    float acc0 = 0.f, acc1 = 0.f, acc2 = 0.f, acc3 = 0.f;
    const int myh = t >> 6;   // thread t owns channels 4t..4t+3, all in head t/64
    for (int bs = 0; bs < deg; bs += 64) {
        const int cnt = min(64, deg - bs);
        if (wave == 0 && lane < cnt) {
            const int e = eid[beg + bs + lane];
            const int s = ei[e];
            src_sh[lane] = s;
            #pragma unroll
            for (int h = 0; h < HEADS; ++h) {
                float v = a_s[s * HEADS + h] + a_d[n * HEADS + h];
                v = v > 0.f ? v : NEG_SLOPE * v;
                al_sh[lane][h] = __expf(v - m_sh[h]) / den_sh[h];
            }
        }
        __syncthreads();
        for (int k = 0; k < cnt; ++k) {
            const int s = src_sh[k];
            const float al = al_sh[k][myh];
            const ushort4 hv = *((const ushort4*)(h1 + (size_t)s * H1DIM) + t);
            acc0 += u2f(hv.x) * al; acc1 += u2f(hv.y) * al;
            acc2 += u2f(hv.z) * al; acc3 += u2f(hv.w) * al;
        }
        __syncthreads();
    }
    float v0 = acc0 + bias[t * 4 + 0];
    float v1 = acc1 + bias[t * 4 + 1];
    float v2 = acc2 + bias[t * 4 + 2];
    float v3 = acc3 + bias[t * 4 + 3];
    v0 = v0 > 0.f ? v0 : expm1f(v0);
    v1 = v1 > 0.f ? v1 : expm1f(v1);
    v2 = v2 > 0.f ? v2 : expm1f(v2);
    v3 = v3 > 0.f ? v3 : expm1f(v3);
    bf16* op = outp + (size_t)n * H1DIM + t * 4;
    op[0] = __float2bfloat16(v0); op[1] = __float2bfloat16(v1);
    op[2] = __float2bfloat16(v2); op[3] = __float2bfloat16(v3);
}

// ---------------- layer 2: per-node softmax + gather + bias, fp32 out ----------------
__global__ __launch_bounds__(256) void gat_gather2(
    const int* __restrict__ ei, const int* __restrict__ offs, const int* __restrict__ eid,
    const bf16* __restrict__ h2, const float* __restrict__ a_s, const float* __restrict__ a_d,
    const float* __restrict__ bias, float* __restrict__ outp)
{
    const int n = blockIdx.x;
    const int beg = offs[n];
    const int deg = offs[n + 1] - beg;
    const int t = threadIdx.x, lane = t & 63, wave = t >> 6;
    __shared__ float m_sh, den_sh;
    __shared__ float al_sh[64];
    __shared__ int   src_sh[64];

    if (wave == 0 && deg > 0) {
        const float adn = a_d[n];
        float mx = -INFINITY;
        for (int k = lane; k < deg; k += 64) {
            const int e = eid[beg + k];
            const int s = ei[N_EDGES + e];     // layer-2 message source = edge_index[1]
            float v = a_s[s] + adn;
            v = v > 0.f ? v : NEG_SLOPE * v;
            mx = fmaxf(mx, v);
        }
        #pragma unroll
        for (int o = 32; o > 0; o >>= 1) mx = fmaxf(mx, __shfl_xor(mx, o));
        float sm = 0.f;
        for (int k = lane; k < deg; k += 64) {
            const int e = eid[beg + k];
            const int s = ei[N_EDGES + e];
            float v = a_s[s] + adn;
            v = v > 0.f ? v : NEG_SLOPE * v;
            sm += __expf(v - mx);
        }
        #pragma unroll
        for (int o = 32; o > 0; o >>= 1) sm += __shfl_xor(sm, o);
        if (lane == 0) { m_sh = mx; den_sh = sm + 1e-16f; }
    }
    __syncthreads();

    float acc = 0.f;
    for (int bs = 0; bs < deg; bs += 64) {
        const int cnt = min(64, deg - bs);
        if (wave == 0 && lane < cnt) {
            const int e = eid[beg + bs + lane];
            const int s = ei[N_EDGES + e];
            src_sh[lane] = s;
            float v = a_s[s] + a_d[n];
            v = v > 0.f ? v : NEG_SLOPE * v;
            al_sh[lane] = __expf(v - m_sh) / den_sh;
        }
        __syncthreads();
        for (int k = 0; k < cnt; ++k) {
            acc += b2f(h2[(size_t)src_sh[k] * OUT_C + t]) * al_sh[k];
        }
        __syncthreads();
    }
    outp[(size_t)n * OUT_C + t] = acc + bias[t];
}

extern "C" void kernel_launch(void* const* d_in, const int* in_sizes, int n_in,
                              void* d_out, int out_size, void* d_ws, size_t ws_size,
                              hipStream_t stream) {
    (void)in_sizes; (void)n_in; (void)out_size; (void)ws_size;
    const float* x        = (const float*)d_in[0];
    const int*   ei       = (const int*)d_in[1];   // int32 on device [2, E] (verified round 4)
    const float* W1       = (const float*)d_in[2];
    const float* att_src1 = (const float*)d_in[3];
    const float* att_dst1 = (const float*)d_in[4];
    const float* b1       = (const float*)d_in[5];
    const float* W2       = (const float*)d_in[6];
    const float* att_src2 = (const float*)d_in[7];
    const float* att_dst2 = (const float*)d_in[8];
    const float* b2       = (const float*)d_in[9];
    float* out = (float*)d_out;

    // ---- workspace carve (all 256B-aligned); total ~48 MB ----
    char* base = (char*)d_ws;
    size_t woff = 0;
    auto carve = [&](size_t bytes) -> char* {
        char* p = base + woff;
        woff += (bytes + 255) & ~(size_t)255;
        return p;
    };
    bf16* h1   = (bf16*)carve((size_t)N_NODES * H1DIM * 2);   // 20.48 MB
    bf16* a2   = (bf16*)carve((size_t)N_NODES * H1DIM * 2);   // 20.48 MB
    bf16* h2   = (bf16*)carve((size_t)N_NODES * OUT_C * 2);   //  5.12 MB
    float* as1 = (float*)carve((size_t)N_NODES * HEADS * 4);
    float* ad1 = (float*)carve((size_t)N_NODES * HEADS * 4);
    float* as2 = (float*)carve((size_t)N_NODES * 4);
    float* ad2 = (float*)carve((size_t)N_NODES * 4);
    int* degs  = (int*)carve((size_t)4 * N_NODES * 4);        // deg_d, deg_s, cur_d, cur_s
    int* deg_d = degs;
    int* deg_s = degs + N_NODES;
    int* cur_d = degs + 2 * N_NODES;
    int* cur_s = degs + 3 * N_NODES;
    int* offs_d = (int*)carve((size_t)(N_NODES + 1) * 4);
    int* offs_s = (int*)carve((size_t)(N_NODES + 1) * 4);
    int* eid_d  = (int*)carve((size_t)N_EDGES * 4);
    int* eid_s  = (int*)carve((size_t)N_EDGES * 4);

    // ---- CSR build ----
    hipMemsetAsync(degs, 0, (size_t)4 * N_NODES * 4, stream);
    count_deg<<<(N_EDGES + 255) / 256, 256, 0, stream>>>(ei, deg_d, deg_s);
    scan_excl<<<1, 1024, 0, stream>>>(deg_d, offs_d, N_NODES);
    scan_excl<<<1, 1024, 0, stream>>>(deg_s, offs_s, N_NODES);
    fill_csr<<<(N_EDGES + 255) / 256, 256, 0, stream>>>(ei, offs_d, offs_s, cur_d, cur_s, eid_d, eid_s);

    // ---- layer 1 ----
    gemm_any<float, float><<<dim3(H1DIM / 64, (N_NODES + 63) / 64), 256, 0, stream>>>(
        x, W1, h1, N_NODES, H1DIM, IN_C);
    att_dots<<<(N_NODES * HEADS + 3) / 4, 256, 0, stream>>>(
        h1, att_src1, att_dst1, as1, ad1, N_NODES * HEADS, HEADS);
    gat_gather1<<<N_NODES, 256, 0, stream>>>(ei, offs_d, eid_d, h1, as1, ad1, b1, a2);

    // ---- layer 2 ----
    gemm_any<bf16, float><<<dim3(OUT_C / 64, (N_NODES + 63) / 64), 256, 0, stream>>>(
        a2, W2, h2, N_NODES, OUT_C, H1DIM);
    att_dots<<<(N_NODES + 3) / 4, 256, 0, stream>>>(
        h2, att_src2, att_dst2, as2, ad2, N_NODES, 1);
    gat_gather2<<<N_NODES, 256, 0, stream>>>(ei, offs_s, eid_s, h2, as2, ad2, b2, out);
}

// Round 6
// 334.145 us; speedup vs baseline: 7.4298x; 1.8359x over previous
//
#include <hip/hip_runtime.h>
#include <hip/hip_bf16.h>
#include <math.h>

typedef __hip_bfloat16 bf16;
typedef __attribute__((ext_vector_type(8))) short bf16x8;
typedef __attribute__((ext_vector_type(4))) float f32x4;

#define N_NODES 10000
#define N_EDGES 160000
#define IN_C    768
#define H1DIM   1024      // HEADS * HID
#define HEADS   4
#define OUT_C   256
#define NEG_SLOPE 0.2f

__device__ __forceinline__ float b2f(bf16 v) { return __bfloat162float(v); }
__device__ __forceinline__ float u2f(unsigned short u) { return __uint_as_float(((unsigned)u) << 16); }

// ---------------- prep: fp32 -> bf16 convert ----------------
__global__ void cvt_bf16(const float* __restrict__ src, bf16* __restrict__ dst, int n4) {
    const int i = (blockIdx.x * blockDim.x + threadIdx.x);
    if (i >= n4) return;
    const float4 v = *((const float4*)src + i);
    bf16* d = dst + i * 4;
    d[0] = __float2bfloat16(v.x); d[1] = __float2bfloat16(v.y);
    d[2] = __float2bfloat16(v.z); d[3] = __float2bfloat16(v.w);
}

// transpose + convert: src [R][C] fp32 -> dst [C][R] bf16.  R,C multiples of 32.
__global__ __launch_bounds__(256) void transpose_bf16(const float* __restrict__ src,
                                                      bf16* __restrict__ dst, int R, int C) {
    __shared__ float tile[32][33];
    const int bc = blockIdx.x * 32;   // col base in src
    const int br = blockIdx.y * 32;   // row base in src
    const int tx = threadIdx.x & 31, ty = threadIdx.x >> 5;   // ty 0..7
    #pragma unroll
    for (int i = ty; i < 32; i += 8)
        tile[i][tx] = src[(size_t)(br + i) * C + bc + tx];
    __syncthreads();
    #pragma unroll
    for (int i = ty; i < 32; i += 8)
        dst[(size_t)(bc + i) * R + br + tx] = __float2bfloat16(tile[tx][i]);
}

// ---------------- CSR build ----------------
__global__ void count_deg(const int* __restrict__ ei, int* __restrict__ deg_d, int* __restrict__ deg_s) {
    const int e = blockIdx.x * blockDim.x + threadIdx.x;
    if (e >= N_EDGES) return;
    atomicAdd(&deg_d[ei[N_EDGES + e]], 1);   // layer-1 segment: edge_index[1]
    atomicAdd(&deg_s[ei[e]], 1);             // layer-2 segment: edge_index[0]
}

__global__ __launch_bounds__(1024) void scan_excl(const int* __restrict__ deg, int* __restrict__ offs, int n) {
    __shared__ int sh[1024];
    __shared__ int carry_sh;
    const int t = threadIdx.x;
    if (t == 0) carry_sh = 0;
    __syncthreads();
    for (int base = 0; base < n; base += 1024) {
        const int i = base + t;
        const int v = (i < n) ? deg[i] : 0;
        sh[t] = v;
        __syncthreads();
        for (int o = 1; o < 1024; o <<= 1) {
            const int x = (t >= o) ? sh[t - o] : 0;
            __syncthreads();
            sh[t] += x;
            __syncthreads();
        }
        const int carry = carry_sh;
        if (i < n) offs[i] = carry + sh[t] - v;   // exclusive
        __syncthreads();
        if (t == 0) carry_sh = carry + sh[1023];
        __syncthreads();
    }
    if (t == 0) offs[n] = carry_sh;
}

__global__ void fill_csr(const int* __restrict__ ei,
                         const int* __restrict__ offs_d, const int* __restrict__ offs_s,
                         int* __restrict__ cur_d, int* __restrict__ cur_s,
                         int* __restrict__ eid_d, int* __restrict__ eid_s) {
    const int e = blockIdx.x * blockDim.x + threadIdx.x;
    if (e >= N_EDGES) return;
    const int d = ei[N_EDGES + e];
    const int p = atomicAdd(&cur_d[d], 1);
    eid_d[offs_d[d] + p] = e;
    const int s = ei[e];
    const int q = atomicAdd(&cur_s[s], 1);
    eid_s[offs_s[s] + q] = e;
}

// ---------------- MFMA NT GEMM: C[M,N] = A[M,K] @ Bt[N,K]^T ----------------
// A, Bt bf16 row-major along K; C bf16. Tile 64x64, BK=32, 4 waves of 32x32.
// LDS chunk layout: 16B chunk (row, seg) at position row*5+seg (stride-5 kills
// bank conflicts on both staging writes and b128 fragment reads).
__global__ __launch_bounds__(256) void gemm_mfma(const bf16* __restrict__ A,
                                                 const bf16* __restrict__ Bt,
                                                 bf16* __restrict__ C,
                                                 int M, int N, int K) {
    __shared__ short lds_a[64 * 5 * 8];
    __shared__ short lds_b[64 * 5 * 8];
    const int bm = blockIdx.y * 64;
    const int bn = blockIdx.x * 64;
    const int t = threadIdx.x;
    const int lane = t & 63;
    const int wv = t >> 6;
    const int wr = (wv & 1) * 32;    // wave row offset in tile
    const int wc = (wv >> 1) * 32;   // wave col offset in tile
    const int fm = lane & 15;        // fragment row/col index
    const int fq = lane >> 4;        // fragment k-quad

    const short* a0p = lds_a + ((wr + fm) * 5 + fq) * 8;
    const short* a1p = a0p + 16 * 5 * 8;
    const short* b0p = lds_b + ((wc + fm) * 5 + fq) * 8;
    const short* b1p = b0p + 16 * 5 * 8;

    const int srow = t >> 2;         // 0..63
    const int sseg = t & 3;          // 0..3  (k chunk of 8)
    short* sa = lds_a + (srow * 5 + sseg) * 8;
    short* sb = lds_b + (srow * 5 + sseg) * 8;
    const bool arow_ok = (bm + srow) < M;
    const bf16* gA = A + (size_t)(bm + srow) * K + sseg * 8;
    const bf16* gB = Bt + (size_t)(bn + srow) * K + sseg * 8;

    f32x4 acc00 = {0.f, 0.f, 0.f, 0.f};
    f32x4 acc01 = {0.f, 0.f, 0.f, 0.f};
    f32x4 acc10 = {0.f, 0.f, 0.f, 0.f};
    f32x4 acc11 = {0.f, 0.f, 0.f, 0.f};

    for (int k0 = 0; k0 < K; k0 += 32) {
        uint4 av = {0u, 0u, 0u, 0u};
        if (arow_ok) av = *(const uint4*)(gA + k0);
        const uint4 bv = *(const uint4*)(gB + k0);
        __syncthreads();   // previous iteration's fragment reads done
        *(uint4*)sa = av;
        *(uint4*)sb = bv;
        __syncthreads();
        const bf16x8 a0 = *(const bf16x8*)a0p;
        const bf16x8 a1 = *(const bf16x8*)a1p;
        const bf16x8 b0 = *(const bf16x8*)b0p;
        const bf16x8 b1 = *(const bf16x8*)b1p;
        acc00 = __builtin_amdgcn_mfma_f32_16x16x32_bf16(a0, b0, acc00, 0, 0, 0);
        acc01 = __builtin_amdgcn_mfma_f32_16x16x32_bf16(a0, b1, acc01, 0, 0, 0);
        acc10 = __builtin_amdgcn_mfma_f32_16x16x32_bf16(a1, b0, acc10, 0, 0, 0);
        acc11 = __builtin_amdgcn_mfma_f32_16x16x32_bf16(a1, b1, acc11, 0, 0, 0);
    }

    // C/D layout: col = lane&15, row = (lane>>4)*4 + reg
    const int cn = bn + wc + fm;
    const int rb = bm + wr + fq * 4;
    #pragma unroll
    for (int r = 0; r < 4; ++r) {
        const int row0 = rb + r;
        if (row0 < M) {
            C[(size_t)row0 * N + cn]      = __float2bfloat16(acc00[r]);
            C[(size_t)row0 * N + cn + 16] = __float2bfloat16(acc01[r]);
        }
        const int row1 = rb + 16 + r;
        if (row1 < M) {
            C[(size_t)row1 * N + cn]      = __float2bfloat16(acc10[r]);
            C[(size_t)row1 * N + cn + 16] = __float2bfloat16(acc11[r]);
        }
    }
}

// ---------------- attention dots: one wave per row of 256 ----------------
__global__ __launch_bounds__(256) void att_dots(const bf16* __restrict__ h,
                                                const float* __restrict__ ws_,
                                                const float* __restrict__ wd_,
                                                float* __restrict__ a_s,
                                                float* __restrict__ a_d,
                                                int rows, int heads) {
    const int r = blockIdx.x * 4 + (threadIdx.x >> 6);
    if (r >= rows) return;
    const int lane = threadIdx.x & 63;
    const int hd = r % heads;
    const bf16* hp = h + (size_t)r * 256 + lane * 4;
    const float* sp = ws_ + hd * 256 + lane * 4;
    const float* dp = wd_ + hd * 256 + lane * 4;
    float ss = 0.f, sd = 0.f;
    #pragma unroll
    for (int i = 0; i < 4; ++i) {
        const float v = b2f(hp[i]);
        ss += v * sp[i];
        sd += v * dp[i];
    }
    #pragma unroll
    for (int o = 32; o > 0; o >>= 1) {
        ss += __shfl_xor(ss, o);
        sd += __shfl_xor(sd, o);
    }
    if (lane == 0) { a_s[r] = ss; a_d[r] = sd; }
}

// ---------------- layer 1: per-node softmax + gather + bias + ELU ----------------
__global__ __launch_bounds__(256) void gat_gather1(
    const int* __restrict__ ei, const int* __restrict__ offs, const int* __restrict__ eid,
    const bf16* __restrict__ h1, const float* __restrict__ a_s, const float* __restrict__ a_d,
    const float* __restrict__ bias, bf16* __restrict__ outp)
{
    const int n = blockIdx.x;
    const int beg = offs[n];
    const int deg = offs[n + 1] - beg;
    const int t = threadIdx.x, lane = t & 63, wave = t >> 6;
    __shared__ float m_sh[HEADS], den_sh[HEADS];
    __shared__ float al_sh[64][HEADS];
    __shared__ int   src_sh[64];

    if (wave == 0 && deg > 0) {
        float adv[HEADS];
        #pragma unroll
        for (int h = 0; h < HEADS; ++h) adv[h] = a_d[n * HEADS + h];
        float mx[HEADS];
        #pragma unroll
        for (int h = 0; h < HEADS; ++h) mx[h] = -INFINITY;
        for (int k = lane; k < deg; k += 64) {
            const int e = eid[beg + k];
            const int s = ei[e];
            #pragma unroll
            for (int h = 0; h < HEADS; ++h) {
                float v = a_s[s * HEADS + h] + adv[h];
                v = v > 0.f ? v : NEG_SLOPE * v;
                mx[h] = fmaxf(mx[h], v);
            }
        }
        #pragma unroll
        for (int o = 32; o > 0; o >>= 1)
            #pragma unroll
            for (int h = 0; h < HEADS; ++h) mx[h] = fmaxf(mx[h], __shfl_xor(mx[h], o));
        float sm[HEADS] = {0.f, 0.f, 0.f, 0.f};
        for (int k = lane; k < deg; k += 64) {
            const int e = eid[beg + k];
            const int s = ei[e];
            #pragma unroll
            for (int h = 0; h < HEADS; ++h) {
                float v = a_s[s * HEADS + h] + adv[h];
                v = v > 0.f ? v : NEG_SLOPE * v;
                sm[h] += __expf(v - mx[h]);
            }
        }
        #pragma unroll
        for (int o = 32; o > 0; o >>= 1)
            #pragma unroll
            for (int h = 0; h < HEADS; ++h) sm[h] += __shfl_xor(sm[h], o);
        if (lane == 0) {
            #pragma unroll
            for (int h = 0; h < HEADS; ++h) { m_sh[h] = mx[h]; den_sh[h] = sm[h] + 1e-16f; }
        }
    }
    __syncthreads();

    float acc0 = 0.f, acc1 = 0.f, acc2 = 0.f, acc3 = 0.f;
    const int myh = t >> 6;   // thread t owns channels 4t..4t+3, all in head t/64
    for (int bs = 0; bs < deg; bs += 64) {
        const int cnt = min(64, deg - bs);
        if (wave == 0 && lane < cnt) {
            const int e = eid[beg + bs + lane];
            const int s = ei[e];
            src_sh[lane] = s;
            #pragma unroll
            for (int h = 0; h < HEADS; ++h) {
                float v = a_s[s * HEADS + h] + a_d[n * HEADS + h];
                v = v > 0.f ? v : NEG_SLOPE * v;
                al_sh[lane][h] = __expf(v - m_sh[h]) / den_sh[h];
            }
        }
        __syncthreads();
        for (int k = 0; k < cnt; ++k) {
            const int s = src_sh[k];
            const float al = al_sh[k][myh];
            const ushort4 hv = *((const ushort4*)(h1 + (size_t)s * H1DIM) + t);
            acc0 += u2f(hv.x) * al; acc1 += u2f(hv.y) * al;
            acc2 += u2f(hv.z) * al; acc3 += u2f(hv.w) * al;
        }
        __syncthreads();
    }
    float v0 = acc0 + bias[t * 4 + 0];
    float v1 = acc1 + bias[t * 4 + 1];
    float v2 = acc2 + bias[t * 4 + 2];
    float v3 = acc3 + bias[t * 4 + 3];
    v0 = v0 > 0.f ? v0 : expm1f(v0);
    v1 = v1 > 0.f ? v1 : expm1f(v1);
    v2 = v2 > 0.f ? v2 : expm1f(v2);
    v3 = v3 > 0.f ? v3 : expm1f(v3);
    bf16* op = outp + (size_t)n * H1DIM + t * 4;
    op[0] = __float2bfloat16(v0); op[1] = __float2bfloat16(v1);
    op[2] = __float2bfloat16(v2); op[3] = __float2bfloat16(v3);
}

// ---------------- layer 2: per-node softmax + gather + bias, fp32 out ----------------
__global__ __launch_bounds__(256) void gat_gather2(
    const int* __restrict__ ei, const int* __restrict__ offs, const int* __restrict__ eid,
    const bf16* __restrict__ h2, const float* __restrict__ a_s, const float* __restrict__ a_d,
    const float* __restrict__ bias, float* __restrict__ outp)
{
    const int n = blockIdx.x;
    const int beg = offs[n];
    const int deg = offs[n + 1] - beg;
    const int t = threadIdx.x, lane = t & 63, wave = t >> 6;
    __shared__ float m_sh, den_sh;
    __shared__ float al_sh[64];
    __shared__ int   src_sh[64];

    if (wave == 0 && deg > 0) {
        const float adn = a_d[n];
        float mx = -INFINITY;
        for (int k = lane; k < deg; k += 64) {
            const int e = eid[beg + k];
            const int s = ei[N_EDGES + e];     // layer-2 message source = edge_index[1]
            float v = a_s[s] + adn;
            v = v > 0.f ? v : NEG_SLOPE * v;
            mx = fmaxf(mx, v);
        }
        #pragma unroll
        for (int o = 32; o > 0; o >>= 1) mx = fmaxf(mx, __shfl_xor(mx, o));
        float sm = 0.f;
        for (int k = lane; k < deg; k += 64) {
            const int e = eid[beg + k];
            const int s = ei[N_EDGES + e];
            float v = a_s[s] + adn;
            v = v > 0.f ? v : NEG_SLOPE * v;
            sm += __expf(v - mx);
        }
        #pragma unroll
        for (int o = 32; o > 0; o >>= 1) sm += __shfl_xor(sm, o);
        if (lane == 0) { m_sh = mx; den_sh = sm + 1e-16f; }
    }
    __syncthreads();

    float acc = 0.f;
    for (int bs = 0; bs < deg; bs += 64) {
        const int cnt = min(64, deg - bs);
        if (wave == 0 && lane < cnt) {
            const int e = eid[beg + bs + lane];
            const int s = ei[N_EDGES + e];
            src_sh[lane] = s;
            float v = a_s[s] + a_d[n];
            v = v > 0.f ? v : NEG_SLOPE * v;
            al_sh[lane] = __expf(v - m_sh) / den_sh;
        }
        __syncthreads();
        for (int k = 0; k < cnt; ++k) {
            acc += b2f(h2[(size_t)src_sh[k] * OUT_C + t]) * al_sh[k];
        }
        __syncthreads();
    }
    outp[(size_t)n * OUT_C + t] = acc + bias[t];
}

extern "C" void kernel_launch(void* const* d_in, const int* in_sizes, int n_in,
                              void* d_out, int out_size, void* d_ws, size_t ws_size,
                              hipStream_t stream) {
    (void)in_sizes; (void)n_in; (void)out_size; (void)ws_size;
    const float* x        = (const float*)d_in[0];
    const int*   ei       = (const int*)d_in[1];   // int32 [2,E] (verified round 4)
    const float* W1       = (const float*)d_in[2];
    const float* att_src1 = (const float*)d_in[3];
    const float* att_dst1 = (const float*)d_in[4];
    const float* b1       = (const float*)d_in[5];
    const float* W2       = (const float*)d_in[6];
    const float* att_src2 = (const float*)d_in[7];
    const float* att_dst2 = (const float*)d_in[8];
    const float* b2       = (const float*)d_in[9];
    float* out = (float*)d_out;

    // ---- workspace carve (all 256B-aligned) ----
    char* base = (char*)d_ws;
    size_t woff = 0;
    auto carve = [&](size_t bytes) -> char* {
        char* p = base + woff;
        woff += (bytes + 255) & ~(size_t)255;
        return p;
    };
    bf16* h1   = (bf16*)carve((size_t)N_NODES * H1DIM * 2);   // 20.48 MB
    bf16* a2   = (bf16*)carve((size_t)N_NODES * H1DIM * 2);   // 20.48 MB
    bf16* h2   = (bf16*)carve((size_t)N_NODES * OUT_C * 2);   //  5.12 MB
    bf16* xb   = (bf16*)carve((size_t)N_NODES * IN_C * 2);    // 15.36 MB  x in bf16
    bf16* W1t  = (bf16*)carve((size_t)H1DIM * IN_C * 2);      //  1.57 MB  [1024][768]
    bf16* W2t  = (bf16*)carve((size_t)OUT_C * H1DIM * 2);     //  0.52 MB  [256][1024]
    float* as1 = (float*)carve((size_t)N_NODES * HEADS * 4);
    float* ad1 = (float*)carve((size_t)N_NODES * HEADS * 4);
    float* as2 = (float*)carve((size_t)N_NODES * 4);
    float* ad2 = (float*)carve((size_t)N_NODES * 4);
    int* degs  = (int*)carve((size_t)4 * N_NODES * 4);        // deg_d, deg_s, cur_d, cur_s
    int* deg_d = degs;
    int* deg_s = degs + N_NODES;
    int* cur_d = degs + 2 * N_NODES;
    int* cur_s = degs + 3 * N_NODES;
    int* offs_d = (int*)carve((size_t)(N_NODES + 1) * 4);
    int* offs_s = (int*)carve((size_t)(N_NODES + 1) * 4);
    int* eid_d  = (int*)carve((size_t)N_EDGES * 4);
    int* eid_s  = (int*)carve((size_t)N_EDGES * 4);

    // ---- prep: bf16 conversions (overlap-friendly, all tiny) ----
    cvt_bf16<<<(N_NODES * IN_C / 4 + 255) / 256, 256, 0, stream>>>(x, xb, N_NODES * IN_C / 4);
    transpose_bf16<<<dim3(H1DIM / 32, IN_C / 32), 256, 0, stream>>>(W1, W1t, IN_C, H1DIM);
    transpose_bf16<<<dim3(OUT_C / 32, H1DIM / 32), 256, 0, stream>>>(W2, W2t, H1DIM, OUT_C);

    // ---- CSR build ----
    hipMemsetAsync(degs, 0, (size_t)4 * N_NODES * 4, stream);
    count_deg<<<(N_EDGES + 255) / 256, 256, 0, stream>>>(ei, deg_d, deg_s);
    scan_excl<<<1, 1024, 0, stream>>>(deg_d, offs_d, N_NODES);
    scan_excl<<<1, 1024, 0, stream>>>(deg_s, offs_s, N_NODES);
    fill_csr<<<(N_EDGES + 255) / 256, 256, 0, stream>>>(ei, offs_d, offs_s, cur_d, cur_s, eid_d, eid_s);

    // ---- layer 1 ----
    gemm_mfma<<<dim3(H1DIM / 64, (N_NODES + 63) / 64), 256, 0, stream>>>(
        xb, W1t, h1, N_NODES, H1DIM, IN_C);
    att_dots<<<(N_NODES * HEADS + 3) / 4, 256, 0, stream>>>(
        h1, att_src1, att_dst1, as1, ad1, N_NODES * HEADS, HEADS);
    gat_gather1<<<N_NODES, 256, 0, stream>>>(ei, offs_d, eid_d, h1, as1, ad1, b1, a2);

    // ---- layer 2 ----
    gemm_mfma<<<dim3(OUT_C / 64, (N_NODES + 63) / 64), 256, 0, stream>>>(
        a2, W2t, h2, N_NODES, OUT_C, H1DIM);
    att_dots<<<(N_NODES + 3) / 4, 256, 0, stream>>>(
        h2, att_src2, att_dst2, as2, ad2, N_NODES, 1);
    gat_gather2<<<N_NODES, 256, 0, stream>>>(ei, offs_s, eid_s, h2, as2, ad2, b2, out);
}